// Round 5
// baseline (340.011 us; speedup 1.0000x reference)
//
#include <hip/hip_runtime.h>
#include <hip/hip_fp16.h>

#define DEV __device__ __forceinline__

using half8 = __attribute__((ext_vector_type(8))) _Float16;
using half4 = __attribute__((ext_vector_type(4))) _Float16;
using half2v = __attribute__((ext_vector_type(2))) _Float16;
using fp16x2 = __attribute__((ext_vector_type(2))) __fp16;
using f32x4 = __attribute__((ext_vector_type(4))) float;

// async global->LDS, 16B per lane. LDS dest is wave-uniform base + lane*16B.
DEV void gload_lds16(const void* g, void* l) {
  __builtin_amdgcn_global_load_lds((const __attribute__((address_space(1))) unsigned int*)g,
                                   (__attribute__((address_space(3))) unsigned int*)l,
                                   16, 0, 0);
}

DEV f32x4 mfma16x32(half8 a, half8 b, f32x4 c) {
  return __builtin_amdgcn_mfma_f32_16x16x32_f16(a, b, c, 0, 0, 0);
}

// 8x f32 -> half8 via packed RTZ converts (2 VALU-elems/op, no pack movs)
DEV half8 cvt8(f32x4 lo, f32x4 hi) {
  half2v p0 = __builtin_bit_cast(half2v, __builtin_amdgcn_cvt_pkrtz(lo[0], lo[1]));
  half2v p1 = __builtin_bit_cast(half2v, __builtin_amdgcn_cvt_pkrtz(lo[2], lo[3]));
  half2v p2 = __builtin_bit_cast(half2v, __builtin_amdgcn_cvt_pkrtz(hi[0], hi[1]));
  half2v p3 = __builtin_bit_cast(half2v, __builtin_amdgcn_cvt_pkrtz(hi[2], hi[3]));
  half4 q0 = __builtin_shufflevector(p0, p1, 0, 1, 2, 3);
  half4 q1 = __builtin_shufflevector(p2, p3, 0, 1, 2, 3);
  return __builtin_shufflevector(q0, q1, 0, 1, 2, 3, 4, 5, 6, 7);
}

// ---------------- f32 -> f16 (weights only now: 3 x 1M elems) ----------------
__global__ void conv3_f32_f16(const float* __restrict__ s0, const float* __restrict__ s1,
                              const float* __restrict__ s2, _Float16* __restrict__ d0,
                              _Float16* __restrict__ d1, _Float16* __restrict__ d2, int n) {
  const float* s = blockIdx.z == 0 ? s0 : (blockIdx.z == 1 ? s1 : s2);
  _Float16* d = blockIdx.z == 0 ? d0 : (blockIdx.z == 1 ? d1 : d2);
  int i = (blockIdx.x * 256 + threadIdx.x) * 8;
  if (i >= n) return;
  float4 a = *(const float4*)(s + i);
  float4 b = *(const float4*)(s + i + 4);
  half8 h;
  h[0] = (_Float16)a.x; h[1] = (_Float16)a.y; h[2] = (_Float16)a.z; h[3] = (_Float16)a.w;
  h[4] = (_Float16)b.x; h[5] = (_Float16)b.y; h[6] = (_Float16)b.z; h[7] = (_Float16)b.w;
  *(half8*)(d + i) = h;
}

// ---------------- zero vt pad columns s=144..159 (must be finite for PV) -------------
__global__ void vt_pad_zero(_Float16* __restrict__ vt) {
  int i = blockIdx.x * 256 + threadIdx.x;   // 131072 (b,e) rows
  _Float16* p = vt + (size_t)i * 160 + 144;
  *(half8*)p = (half8){};
  *(half8*)(p + 8) = (half8){};
}

// ---------------- relative-position bias rp[s][t] ----------------
__global__ __launch_bounds__(192) void rp_kernel(const float* __restrict__ Wlin,
                                                 const float* __restrict__ wg,
                                                 float* __restrict__ rp) {
  int s = blockIdx.x, t = threadIdx.x;
  if (t >= 144) return;
  int rs = s / 12, cs = s % 12, rt = t / 12, ct = t % 12;
  float dx = (cs - ct) / 12.f, dy = (rs - rt) / 12.f;
  float ax = (dx > 0.f) ? 0.5f : (dx < 0.f ? -0.5f : 0.f);
  float ay = (dy > 0.f) ? 0.5f : (dy < 0.f ? -0.5f : 0.f);
  float lx = fabsf(logf(fabsf(dx) + 0.5f));
  float ly = fabsf(logf(fabsf(dy) + 0.5f));
  float a0 = 0.f, a1 = 0.f, a2 = 0.f, a3 = 0.f;
  const float* wgs = wg + s * 1024;
  for (int d = 0; d < 1024; d += 4) {
#pragma unroll
    for (int u = 0; u < 4; ++u) {
      float4 w = *(const float4*)(Wlin + (d + u) * 4);
      float dot = lx * w.x + ly * w.y + ax * w.z + ay * w.w;
      dot = dot > 0.f ? dot : 0.f;
      float p = dot * wgs[d + u];
      if (u == 0) a0 += p; else if (u == 1) a1 += p; else if (u == 2) a2 += p; else a3 += p;
    }
  }
  float acc = (a0 + a1) + (a2 + a3);
  rp[s * 144 + t] = acc > 0.f ? acc : 0.f;
}

// ---------------- projection GEMM: C = relu(A32 * B^T + bias), A f32 / W f16 ----------
// 128(M)x128(N) block, 4 waves (2x2), wave-tile 64x64 (acc 4x4), BK=32.
// SAME proven schedule constants as the r4/R0 kernel: 24KB slots x3, 6 gloads/wave/slot,
// depth-2 prefetch, counted vmcnt(6), 2 blocks/CU. The f32->f16 conversion of A is fused
// at FRAGMENT-READ time (v_cvt_pkrtz), staging stays pure async gload_lds16 (no ds_write,
// no reg staging — the R2 failure mode).
// A chunks: 8 rows x 32 f32 = 1KB; per-row rotation of 16B slots: stored[s]=orig[(s+r)&7]
//   (read granule (p-r)&7 -> <=2 lanes/bank quad = free).
// B chunks: 16 rows x 32 f16 = 1KB, proven cg8/rdoff rotation.
// Tail: pointers roll back 2 chunks at t==29 so the depth-2 prefetch of iters 30/31
//   re-reads valid K-chunks (A is d_in; must not read past the input tensor).
// z == vtz writes the TRANSPOSED output into vt[(b*1024+e)*160+s] instead of C.
__global__ __launch_bounds__(256, 2) void gemm_proj(
    const float* __restrict__ A0, const float* __restrict__ A1,
    const float* __restrict__ A2, const _Float16* __restrict__ w0q,
    const _Float16* __restrict__ w1q, const _Float16* __restrict__ w2q,
    const float* __restrict__ bi0, const float* __restrict__ bi1,
    const float* __restrict__ bi2, _Float16* __restrict__ c0q,
    _Float16* __restrict__ c1q, _Float16* __restrict__ c2q,
    _Float16* __restrict__ vtp, int vtz) {
  const float* A = blockIdx.z == 0 ? A0 : (blockIdx.z == 1 ? A1 : A2);
  const _Float16* W = blockIdx.z == 0 ? w0q : (blockIdx.z == 1 ? w1q : w2q);
  const float* bias = blockIdx.z == 0 ? bi0 : (blockIdx.z == 1 ? bi1 : bi2);
  _Float16* C = blockIdx.z == 0 ? c0q : (blockIdx.z == 1 ? c1q : c2q);

  __shared__ __align__(16) char lds[73728];  // 3 x 24KB slots (A 16KB f32 + B 8KB f16)
  int tid = threadIdx.x, wid = tid >> 6, lane = tid & 63;
  int lin = blockIdx.y * 8 + blockIdx.x;     // 0..1151 ; XCD-chunked, 144 per XCD
  int local = lin >> 3;
  int mt = (lin & 7) * 18 + (local >> 3), nt = local & 7;
  int m0 = mt * 128, n0 = nt * 128;

  // B-path helpers (f16, proven)
  int r4l = lane >> 2, c4 = lane & 3;
  int cg8 = ((c4 + (r4l >> 1)) & 3) * 8;                 // rotated source kslot (f16)
  int lr = lane & 15, lg = lane >> 4;
  int rdoff = lr * 64 + ((lg - (lr >> 1)) & 3) * 16;     // B fragment read offset (bytes)
  // A-path helpers (f32, 8-row chunks, 16B slot rotation rot=row&7)
  int ar = lane >> 3, ac = lane & 7;
  int acs = ((ac + ar) & 7) * 4;                          // source k-offset (f32 elems)
  int rr = lr & 7, sub = lr >> 3;
  int s0off = rr * 128 + (((2 * lg - rr) & 7) << 4);      // frag read: first 16B quad
  int s1off = rr * 128 + (((2 * lg + 1 - rr) & 7) << 4);  // second 16B quad

  // A: 16 chunks (8 rows each); wave stages chunks c*4+wid, c=0..3.
  const float* gpA[4];
#pragma unroll
  for (int c = 0; c < 4; ++c)
    gpA[c] = A + (size_t)(m0 + (c * 4 + wid) * 8 + ar) * 1024 + acs;
  // B: 8 chunks (16 rows each); wave stages chunks c*4+wid, c=0..1.
  const _Float16* gpB[2];
#pragma unroll
  for (int c = 0; c < 2; ++c)
    gpB[c] = W + (size_t)(n0 + (c * 4 + wid) * 16 + r4l) * 1024 + cg8;

  char *sl0 = lds, *sl1 = lds + 24576, *sl2 = lds + 49152;
  auto issue = [&](char* slot) {
#pragma unroll
    for (int c = 0; c < 4; ++c) { gload_lds16(gpA[c], slot + (c * 4 + wid) * 1024); gpA[c] += 32; }
#pragma unroll
    for (int c = 0; c < 2; ++c) { gload_lds16(gpB[c], slot + 16384 + (c * 4 + wid) * 1024); gpB[c] += 32; }
  };
  issue(sl0);
  issue(sl1);
  f32x4 acc[4][4] = {};
  int wm = (wid >> 1) * 64, wn = (wid & 1) * 64;
  int achunk0 = wm >> 3, bchunk0 = wn >> 4;
  for (int t = 0; t < 32; ++t) {
    asm volatile("s_waitcnt vmcnt(6)" ::: "memory");
    __builtin_amdgcn_s_barrier();
    __builtin_amdgcn_sched_barrier(0);
    issue(sl2);
    if (t == 29) {  // rewind so iters 30/31 prefetch valid K-chunks (no OOB on d_in)
#pragma unroll
      for (int c = 0; c < 4; ++c) gpA[c] -= 64;
#pragma unroll
      for (int c = 0; c < 2; ++c) gpB[c] -= 64;
    }
    half8 a[4], b[4];
#pragma unroll
    for (int i = 0; i < 4; ++i) {
      const char* ab = sl0 + (achunk0 + i * 2 + sub) * 1024;
      f32x4 lo = *(const f32x4*)(ab + s0off);
      f32x4 hi = *(const f32x4*)(ab + s1off);
      a[i] = cvt8(lo, hi);
    }
#pragma unroll
    for (int j = 0; j < 4; ++j)
      b[j] = *(const half8*)(sl0 + 16384 + (bchunk0 + j) * 1024 + rdoff);
#pragma unroll
    for (int i = 0; i < 4; ++i)
#pragma unroll
      for (int j = 0; j < 4; ++j)
        acc[i][j] = mfma16x32(b[j], a[i], acc[i][j]);  // swapped: lane holds 4 consec cols
    char* tmp = sl0; sl0 = sl1; sl1 = sl2; sl2 = tmp;
  }
  // epilogue: bias + relu -> f16. Normal z: 8B stores to C. z==vtz: transposed into vt.
  bool tov = (vtp != nullptr) && ((int)blockIdx.z == vtz);
#pragma unroll
  for (int i = 0; i < 4; ++i) {
    int row = m0 + wm + i * 16 + lr;
#pragma unroll
    for (int j = 0; j < 4; ++j) {
      int col = n0 + wn + j * 16 + lg * 4;
      float4 b4 = *(const float4*)(bias + col);
      half4 h;
      float v0 = acc[i][j][0] + b4.x; h[0] = (_Float16)(v0 > 0.f ? v0 : 0.f);
      float v1 = acc[i][j][1] + b4.y; h[1] = (_Float16)(v1 > 0.f ? v1 : 0.f);
      float v2 = acc[i][j][2] + b4.z; h[2] = (_Float16)(v2 > 0.f ? v2 : 0.f);
      float v3 = acc[i][j][3] + b4.w; h[3] = (_Float16)(v3 > 0.f ? v3 : 0.f);
      if (tov) {
        int bb = row / 144, ss = row - bb * 144;
        _Float16* vb = vtp + (size_t)(bb * 1024 + col) * 160 + ss;
        vb[0] = h[0]; vb[160] = h[1]; vb[320] = h[2]; vb[480] = h[3];
      } else {
        *(half4*)(C + (size_t)row * 1024 + col) = h;
      }
    }
  }
}

// ---------------- fused attention per (batch, 48-row third) ----------------
// q,k [18432][1024] f16 ; vt [b*1024+e][160] f16 (pad cols finite) ; rp [144][144] f32
__global__ __launch_bounds__(256) void attn_kernel(const _Float16* __restrict__ q,
                                                   const _Float16* __restrict__ k,
                                                   const _Float16* __restrict__ vt,
                                                   const float* __restrict__ rp,
                                                   float* __restrict__ out) {
  __shared__ __align__(16) char lds[53248];
  // phase1 slots: 0 / 12288 / 24576 (12KB) ; phase2 slots: 0 / 16384 (16KB)
  // sc (f32, stride 152) aliases 0..29184 ; P @36864 (48x168 f16) ; sums @52992
  float* sc = (float*)lds;
  _Float16* P = (_Float16*)(lds + 36864);
  float* sums = (float*)(lds + 52992);

  int tid = threadIdx.x, wid = tid >> 6, lane = tid & 63;
  int lin = blockIdx.y * 3 + blockIdx.x;       // 0..383
  int swz = (lin & 7) * 48 + (lin >> 3);
  int mt3 = swz % 3, b = swz / 3;
  int m0 = mt3 * 48;
  const int nstart_t[4] = {0, 3, 5, 7};
  const int ncnt_t[4]   = {3, 2, 2, 2};
  int ns = nstart_t[wid], nc = ncnt_t[wid];
  int r4l = lane >> 2, c4 = lane & 3;
  int cg8 = ((c4 + (r4l >> 1)) & 3) * 8;
  int lr = lane & 15, lg = lane >> 4;
  int rdoff = lr * 64 + ((lg - (lr >> 1)) & 3) * 16;   // bytes

  // ---- phase 1: scores = q . k^T over K=1024, triple-buffer depth-2 ----
  {
    char *sl0 = lds, *sl1 = lds + 12288, *sl2 = lds + 24576;
    const _Float16* g1[3];
#pragma unroll
    for (int c = 0; c < 3; ++c) {
      int qq = c * 4 + wid;  // 0..2 -> q chunks (48 rows), 3..11 -> k chunks (144 rows)
      g1[c] = (qq < 3) ? q + (size_t)(b * 144 + m0 + qq * 16 + r4l) * 1024 + cg8
                       : k + (size_t)(b * 144 + (qq - 3) * 16 + r4l) * 1024 + cg8;
    }
    auto issue1 = [&](char* slot) {
#pragma unroll
      for (int c = 0; c < 3; ++c) {
        gload_lds16(g1[c], slot + (c * 4 + wid) * 1024);
        g1[c] += 32;
      }
    };
    issue1(sl0);
    issue1(sl1);
    f32x4 acc[3][3] = {};
    for (int t = 0; t < 32; ++t) {
      asm volatile("s_waitcnt vmcnt(3)" ::: "memory");
      __builtin_amdgcn_sched_barrier(0);
      __builtin_amdgcn_s_barrier();
      __builtin_amdgcn_sched_barrier(0);
      issue1(sl2);  // tail garbage stays inside readable ws (kp followed by vt region)
      half8 af[3], bf[3];
#pragma unroll
      for (int i = 0; i < 3; ++i)
        af[i] = *(const half8*)(sl0 + i * 1024 + rdoff);
#pragma unroll
      for (int j = 0; j < 3; ++j)
        if (j < nc)
          bf[j] = *(const half8*)(sl0 + (3 + ns + j) * 1024 + rdoff);
#pragma unroll
      for (int i = 0; i < 3; ++i)
#pragma unroll
        for (int j = 0; j < 3; ++j)
          if (j < nc)
            acc[i][j] = mfma16x32(bf[j], af[i], acc[i][j]);  // swapped
      char* tmp = sl0; sl0 = sl1; sl1 = sl2; sl2 = tmp;
    }
    asm volatile("s_waitcnt vmcnt(0)" ::: "memory");
    __syncthreads();  // straggler prefetches drained before sc aliases the slots
    const float scale = 0.03125f;  // 1024^-0.5
#pragma unroll
    for (int i = 0; i < 3; ++i) {
      int qrow = i * 16 + lr;
#pragma unroll
      for (int j = 0; j < 3; ++j)
        if (j < nc) {
          int kc0 = (ns + j) * 16 + lg * 4;
          float4 rr = *(const float4*)(rp + (m0 + qrow) * 144 + kc0);
          f32x4 vs;
          vs[0] = acc[i][j][0] * scale + rr.x;
          vs[1] = acc[i][j][1] * scale + rr.y;
          vs[2] = acc[i][j][2] * scale + rr.z;
          vs[3] = acc[i][j][3] * scale + rr.w;
          *(f32x4*)(sc + qrow * 152 + kc0) = vs;
        }
    }
  }
  __syncthreads();

  // ---- softmax (unnormalized; sums kept for epilogue) ----
  if (tid < 192) {
    int r = tid >> 2, qd = tid & 3;
    int cb = qd * 36;
    float m = -1e30f;
    for (int c2 = 0; c2 < 36; ++c2) m = fmaxf(m, sc[r * 152 + cb + c2]);
    m = fmaxf(m, __shfl_xor(m, 1));
    m = fmaxf(m, __shfl_xor(m, 2));
    float s = 0.f;
    for (int c2 = 0; c2 < 36; ++c2) {
      float e = __expf(sc[r * 152 + cb + c2] - m);
      s += e;
      P[r * 168 + cb + c2] = (_Float16)e;
    }
    s += __shfl_xor(s, 1);
    s += __shfl_xor(s, 2);
    if (qd == 0) sums[r] = s;
  }
  if (tid < 96) {  // zero-pad P cols 144..159
    int r = tid >> 1, c0 = 144 + (tid & 1) * 8;
    *(half8*)(P + r * 168 + c0) = (half8){};
  }
  __syncthreads();

  // ---- phase 2: out = (P @ V) / sums — 20 uniform K=32 iters, 2 slots depth-1 ----
  char *s0p = lds, *s1p = lds + 16384;
  auto issue2 = [&](int idx, char* slot) {
    int nn0 = (idx / 5) * 256, kk0 = (idx % 5) * 32;
#pragma unroll
    for (int c = 0; c < 4; ++c) {
      int ch = c * 4 + wid;  // 16 chunks of 16 rows
      gload_lds16(vt + (size_t)(b * 1024 + nn0 + ch * 16 + r4l) * 160 + kk0 + cg8,
                  slot + ch * 1024);
    }
  };
  issue2(0, s0p);
  f32x4 o[3][4] = {};
  for (int it = 0; it < 20; ++it) {
    asm volatile("s_waitcnt vmcnt(0)" ::: "memory");
    __builtin_amdgcn_sched_barrier(0);
    __builtin_amdgcn_s_barrier();
    __builtin_amdgcn_sched_barrier(0);
    issue2(it + 1, ((it + 1) & 1) ? s1p : s0p);  // it=19 -> garbage into region after vt
    char* sb = (it & 1) ? s1p : s0p;
    int k0 = (it % 5) * 32;
    half8 af[3], bf[4];
#pragma unroll
    for (int i = 0; i < 3; ++i)
      af[i] = *(const half8*)(P + (i * 16 + lr) * 168 + k0 + lg * 8);
#pragma unroll
    for (int j = 0; j < 4; ++j)
      bf[j] = *(const half8*)(sb + (wid * 4 + j) * 1024 + rdoff);
#pragma unroll
    for (int i = 0; i < 3; ++i)
#pragma unroll
      for (int j = 0; j < 4; ++j)
        o[i][j] = mfma16x32(bf[j], af[i], o[i][j]);  // swapped
    if (it % 5 == 4) {
      int n0 = (it / 5) * 256;
#pragma unroll
      for (int i = 0; i < 3; ++i) {
        int row = i * 16 + lr;
        float inv = 1.f / sums[row];
#pragma unroll
        for (int j = 0; j < 4; ++j) {
          f32x4 vo;
          vo[0] = o[i][j][0] * inv; vo[1] = o[i][j][1] * inv;
          vo[2] = o[i][j][2] * inv; vo[3] = o[i][j][3] * inv;
          *(f32x4*)(out + (size_t)(b * 144 + m0 + row) * 1024 + n0 + wid * 64 + j * 16 + lg * 4) = vo;
          o[i][j] = (f32x4){};
        }
      }
    }
  }
}

extern "C" void kernel_launch(void* const* d_in, const int* in_sizes, int n_in,
                              void* d_out, int out_size, void* d_ws, size_t ws_size,
                              hipStream_t stream) {
  const float* query = (const float*)d_in[0];
  const float* key   = (const float*)d_in[1];
  const float* value = (const float*)d_in[2];
  const float* Wq    = (const float*)d_in[3];
  const float* bq    = (const float*)d_in[4];
  const float* Wk    = (const float*)d_in[5];
  const float* bk    = (const float*)d_in[6];
  const float* Wv    = (const float*)d_in[7];
  const float* bv    = (const float*)d_in[8];
  const float* Wlin  = (const float*)d_in[9];
  const float* wg    = (const float*)d_in[10];
  float* out = (float*)d_out;

  char* ws = (char*)d_ws;
  const size_t NQKV = (size_t)18432 * 1024;            // 37.75 MB as f16
  const size_t NVT  = (size_t)131072 * 160;            // padded vt (40 MB)
  const int    NW   = 1024 * 1024;
  // layout (~122 MB total; fits every harness ws):
  // [W 6MB][rp 128KB][vt 40MB][qp 37.75MB][kp 37.75MB]
  // attn phase2 tail prefetch (~82KB past vt) lands in qp (reads only);
  // attn phase1 tail prefetch (128B past kp) stays inside the ws allocation.
  _Float16* Wqb = (_Float16*)(ws);
  _Float16* Wkb = (_Float16*)(ws + (2u << 20));
  _Float16* Wvb = (_Float16*)(ws + (4u << 20));
  float*    rp  = (float*)(ws + (6u << 20));
  _Float16* vt  = (_Float16*)(ws + (6u << 20) + 131072);
  _Float16* qp  = vt + NVT;
  _Float16* kp  = qp + NQKV;

  dim3 agrid(3, 128);

  // gemm reads f32 inputs directly (A staged as f32, cvt fused at fragment read);
  // only the small weight matrices get a conversion pass.
  conv3_f32_f16<<<dim3(NW / 2048, 1, 3), 256, 0, stream>>>(Wq, Wk, Wv, Wqb, Wkb, Wvb, NW);
  rp_kernel<<<144, 192, 0, stream>>>(Wlin, wg, rp);
  vt_pad_zero<<<512, 256, 0, stream>>>(vt);
  gemm_proj<<<dim3(8, 144, 3), 256, 0, stream>>>(query, key, value, Wqb, Wkb, Wvb,
                                                 bq, bk, bv, qp, kp, kp /*unused z2*/,
                                                 vt, 2);
  attn_kernel<<<agrid, 256, 0, stream>>>(qp, kp, vt, rp, out);
}